// Round 2
// baseline (95.700 us; speedup 1.0000x reference)
//
#include <hip/hip_runtime.h>

#define NPTS 8192
#define NQ   2048
#define NBATCH 8
#define KNN  32
#define R2   0.04f   // fp32 cast of python 0.2**2 (weak-typed to f32 in jnp/np compare)

// Pack pos (AoS, 12B stride) into float4(x,y,z,|p|^2) for single dwordx4 loads.
// Norm computed with explicit round-to-nearest ops, no FMA contraction, in the
// reference's order: (x*x + y*y) + z*z.
__global__ __launch_bounds__(256)
void gg_prep(const float* __restrict__ pos, float4* __restrict__ pack, int total) {
    int i = blockIdx.x * blockDim.x + threadIdx.x;
    if (i >= total) return;
    float x = pos[i * 3 + 0];
    float y = pos[i * 3 + 1];
    float z = pos[i * 3 + 2];
    float n = __fadd_rn(__fadd_rn(__fmul_rn(x, x), __fmul_rn(y, y)), __fmul_rn(z, z));
    pack[i] = make_float4(x, y, z, n);
}

// One wave (64 lanes) per query. Wave scans points in ascending index order,
// 64 at a time; ballot-compacts in-radius hits into out slots; early-exits
// once 32 collected. Distance formula matches reference op order exactly:
//   s = (cn + pn) - 2*dot,  dot = (cx*px + cy*py) + cz*pz
__global__ __launch_bounds__(256)
void gg_ballquery(const float4* __restrict__ pack,
                  const int* __restrict__ centroids,
                  int* __restrict__ out) {
    const int wid  = threadIdx.x >> 6;
    const int lane = threadIdx.x & 63;
    const int q    = blockIdx.x * 4 + wid;          // 0 .. 16383
    const int b    = q >> 11;                       // q / 2048

    const float4* __restrict__ pp = pack + b * NPTS;

    const int cidx = centroids[q];
    const float4 c = pp[cidx];
    const float cx = c.x, cy = c.y, cz = c.z, cn = c.w;

    int* __restrict__ oq = out + q * KNN;
    const unsigned long long below = (1ull << lane) - 1ull;

    int collected = 0;
    int first_idx = NPTS;     // stays N only if zero hits (impossible: centroid dist == 0)

    float4 cur = pp[lane];    // prefetch chunk 0
    #pragma unroll 1
    for (int base = 0; base < NPTS; base += 64) {
        float4 p = cur;
        if (base + 64 < NPTS) cur = pp[base + 64 + lane];   // prefetch next chunk

        float dot = __fadd_rn(__fadd_rn(__fmul_rn(cx, p.x), __fmul_rn(cy, p.y)),
                              __fmul_rn(cz, p.z));
        float s   = __fsub_rn(__fadd_rn(cn, p.w), __fmul_rn(2.0f, dot));
        bool keep = !(s > R2);                      // reference: where(s > R2, N, idx)

        unsigned long long mask = __ballot(keep);
        if (mask) {
            if (collected == 0) first_idx = base + (int)__builtin_ctzll(mask);
            if (keep) {
                int slot = collected + (int)__popcll(mask & below);
                if (slot < KNN) oq[slot] = base + lane;
            }
            collected += (int)__popcll(mask);
            if (collected >= KNN) break;            // wave-uniform early exit
        }
    }

    // Pad tail slots [collected, 32) with the first neighbor index.
    if (collected < KNN) {
        int slot = collected + lane;
        if (slot < KNN) oq[slot] = first_idx;
    }
}

extern "C" void kernel_launch(void* const* d_in, const int* in_sizes, int n_in,
                              void* d_out, int out_size, void* d_ws, size_t ws_size,
                              hipStream_t stream) {
    const float* pos       = (const float*)d_in[0];   // (8, 8192, 3) f32
    const int*   centroids = (const int*)d_in[1];     // (8, 2048) int32 on device
    int*         out       = (int*)d_out;             // (8, 2048, 32) int32

    float4* pack = (float4*)d_ws;                     // 8*8192*16B = 1 MiB scratch

    const int total = NBATCH * NPTS;                  // 65536 points
    gg_prep<<<dim3((total + 255) / 256), dim3(256), 0, stream>>>(pos, pack, total);

    const int nq = NBATCH * NQ;                       // 16384 queries, 4 per block
    gg_ballquery<<<dim3(nq / 4), dim3(256), 0, stream>>>(pack, centroids, out);
}

// Round 3
// 82.019 us; speedup vs baseline: 1.1668x; 1.1668x over previous
//
#include <hip/hip_runtime.h>

#define NPTS 8192
#define NQ   2048
#define NBATCH 8
#define KNN  32
#define R2   0.04f   // fp32 cast of python 0.2**2

// Pack pos (AoS, 12B stride) into float4(x,y,z,|p|^2) for single dwordx4 loads.
// Norm with explicit round-to-nearest ops, no FMA contraction, reference order:
// (x*x + y*y) + z*z.
__global__ __launch_bounds__(256)
void gg_prep(const float* __restrict__ pos, float4* __restrict__ pack, int total) {
    int i = blockIdx.x * blockDim.x + threadIdx.x;
    if (i >= total) return;
    float x = pos[i * 3 + 0];
    float y = pos[i * 3 + 1];
    float z = pos[i * 3 + 2];
    float n = __fadd_rn(__fadd_rn(__fmul_rn(x, x), __fmul_rn(y, y)), __fmul_rn(z, z));
    pack[i] = make_float4(x, y, z, n);
}

// One wave per query. 256 points per iteration: 4 independent dwordx4 loads
// issued one full iteration ahead (256-point-deep prefetch), then 4 ballot
// sub-chunks against resident registers. Early exit per 64-point sub-chunk.
// Distance formula matches reference op order exactly:
//   s = (cn + pn) - 2*dot,  dot = (cx*px + cy*py) + cz*pz
__global__ __launch_bounds__(256)
void gg_ballquery(const float4* __restrict__ pack,
                  const int* __restrict__ centroids,
                  int* __restrict__ out) {
    const int wid  = threadIdx.x >> 6;
    const int lane = threadIdx.x & 63;
    const int q    = blockIdx.x * 4 + wid;          // 0 .. 16383
    const int b    = q >> 11;                       // q / 2048

    const float4* __restrict__ pp = pack + b * NPTS;

    const int cidx = centroids[q];
    const float4 c = pp[cidx];
    const float cx = c.x, cy = c.y, cz = c.z, cn = c.w;

    int* __restrict__ oq = out + q * KNN;
    const unsigned long long below = (1ull << lane) - 1ull;

    int collected = 0;
    int first_idx = NPTS;    // stays N only with zero hits (impossible: centroid dist == 0)

    // Prefetch iteration 0 (points [0, 256))
    float4 c0 = pp[lane];
    float4 c1 = pp[lane + 64];
    float4 c2 = pp[lane + 128];
    float4 c3 = pp[lane + 192];

    #pragma unroll 1
    for (int base = 0; base < NPTS; base += 256) {
        float4 p0 = c0, p1 = c1, p2 = c2, p3 = c3;
        if (base + 256 < NPTS) {                    // prefetch next 256 points
            c0 = pp[base + 256 + lane];
            c1 = pp[base + 320 + lane];
            c2 = pp[base + 384 + lane];
            c3 = pp[base + 448 + lane];
        }

        #pragma unroll
        for (int j = 0; j < 4; ++j) {
            float4 p = (j == 0) ? p0 : (j == 1) ? p1 : (j == 2) ? p2 : p3;
            float dot = __fadd_rn(__fadd_rn(__fmul_rn(cx, p.x), __fmul_rn(cy, p.y)),
                                  __fmul_rn(cz, p.z));
            float s   = __fsub_rn(__fadd_rn(cn, p.w), __fmul_rn(2.0f, dot));
            bool keep = !(s > R2);                  // reference: where(s > R2, N, idx)

            unsigned long long mask = __ballot(keep);
            if (mask) {
                int sub = base + j * 64;
                if (collected == 0) first_idx = sub + (int)__builtin_ctzll(mask);
                if (keep) {
                    int slot = collected + (int)__popcll(mask & below);
                    if (slot < KNN) oq[slot] = sub + lane;
                }
                collected += (int)__popcll(mask);
                if (collected >= KNN) goto done;    // wave-uniform early exit
            }
        }
    }
done:

    // Pad tail slots [collected, 32) with the first neighbor index.
    if (collected < KNN) {
        int slot = collected + lane;
        if (slot < KNN) oq[slot] = first_idx;
    }
}

extern "C" void kernel_launch(void* const* d_in, const int* in_sizes, int n_in,
                              void* d_out, int out_size, void* d_ws, size_t ws_size,
                              hipStream_t stream) {
    const float* pos       = (const float*)d_in[0];   // (8, 8192, 3) f32
    const int*   centroids = (const int*)d_in[1];     // (8, 2048) int32 on device
    int*         out       = (int*)d_out;             // (8, 2048, 32) int32

    float4* pack = (float4*)d_ws;                     // 8*8192*16B = 1 MiB scratch

    const int total = NBATCH * NPTS;                  // 65536 points
    gg_prep<<<dim3((total + 255) / 256), dim3(256), 0, stream>>>(pos, pack, total);

    const int nq = NBATCH * NQ;                       // 16384 queries, 4 per block
    gg_ballquery<<<dim3(nq / 4), dim3(256), 0, stream>>>(pack, centroids, out);
}

// Round 4
// 79.061 us; speedup vs baseline: 1.2105x; 1.0374x over previous
//
#include <hip/hip_runtime.h>

#define NPTS 8192
#define NQ   2048
#define NBATCH 8
#define KNN  32
#define R2   0.04f   // fp32 cast of python 0.2**2

// Pack pos (AoS, 12B stride) into float4(x,y,z,|p|^2). Norm with explicit
// round-to-nearest ops, no FMA contraction, reference order: (x*x+y*y)+z*z.
__global__ __launch_bounds__(256)
void gg_prep(const float* __restrict__ pos, float4* __restrict__ pack, int total) {
    int i = blockIdx.x * blockDim.x + threadIdx.x;
    if (i >= total) return;
    float x = pos[i * 3 + 0];
    float y = pos[i * 3 + 1];
    float z = pos[i * 3 + 2];
    float n = __fadd_rn(__fadd_rn(__fmul_rn(x, x), __fmul_rn(y, y)), __fmul_rn(z, z));
    pack[i] = make_float4(x, y, z, n);
}

// One wave per TWO queries (same batch): each 256-point chunk is loaded once
// and tested against both centroids -> L2 traffic halved. 4 dwordx4 loads
// issued one full iteration (256 pts) ahead. Early exit when BOTH queries
// have 32 hits. Distance formula matches reference op order exactly:
//   s = (cn + pn) - 2*dot,  dot = (cx*px + cy*py) + cz*pz
__global__ __launch_bounds__(256)
void gg_ballquery(const float4* __restrict__ pack,
                  const int* __restrict__ centroids,
                  int* __restrict__ out) {
    const int wid  = threadIdx.x >> 6;
    const int lane = threadIdx.x & 63;
    const int w    = blockIdx.x * 4 + wid;          // wave id: 0 .. 8191
    const int q0   = w * 2;                         // two consecutive queries
    const int b    = q0 >> 11;                      // batch (2048 queries/batch, even)

    const float4* __restrict__ pp = pack + b * NPTS;

    const float4 ca = pp[centroids[q0]];
    const float4 cb = pp[centroids[q0 + 1]];

    int* __restrict__ oa = out + q0 * KNN;
    int* __restrict__ ob = oa + KNN;

    int colA = 0, colB = 0;
    int firstA = NPTS, firstB = NPTS;

    // Prefetch iteration 0 (points [0, 256))
    float4 r0 = pp[lane];
    float4 r1 = pp[lane + 64];
    float4 r2 = pp[lane + 128];
    float4 r3 = pp[lane + 192];

    #pragma unroll 1
    for (int base = 0; base < NPTS; base += 256) {
        float4 p0 = r0, p1 = r1, p2 = r2, p3 = r3;
        if (base + 256 < NPTS) {                    // prefetch next 256 points
            r0 = pp[base + 256 + lane];
            r1 = pp[base + 320 + lane];
            r2 = pp[base + 384 + lane];
            r3 = pp[base + 448 + lane];
        }

        #pragma unroll
        for (int j = 0; j < 4; ++j) {
            float4 p = (j == 0) ? p0 : (j == 1) ? p1 : (j == 2) ? p2 : p3;
            const int sub = base + j * 64;

            if (colA < KNN) {
                float dot = __fadd_rn(__fadd_rn(__fmul_rn(ca.x, p.x), __fmul_rn(ca.y, p.y)),
                                      __fmul_rn(ca.z, p.z));
                float s   = __fsub_rn(__fadd_rn(ca.w, p.w), __fmul_rn(2.0f, dot));
                bool keep = !(s > R2);              // reference: where(s > R2, N, idx)
                unsigned long long mask = __ballot(keep);
                if (mask) {
                    if (colA == 0) firstA = sub + (int)__builtin_ctzll(mask);
                    int prefix = (int)__builtin_amdgcn_mbcnt_hi(
                        (unsigned)(mask >> 32),
                        __builtin_amdgcn_mbcnt_lo((unsigned)mask, 0u));
                    if (keep) {
                        int slot = colA + prefix;
                        if (slot < KNN) oa[slot] = sub + lane;
                    }
                    colA += (int)__popcll(mask);
                }
            }
            if (colB < KNN) {
                float dot = __fadd_rn(__fadd_rn(__fmul_rn(cb.x, p.x), __fmul_rn(cb.y, p.y)),
                                      __fmul_rn(cb.z, p.z));
                float s   = __fsub_rn(__fadd_rn(cb.w, p.w), __fmul_rn(2.0f, dot));
                bool keep = !(s > R2);
                unsigned long long mask = __ballot(keep);
                if (mask) {
                    if (colB == 0) firstB = sub + (int)__builtin_ctzll(mask);
                    int prefix = (int)__builtin_amdgcn_mbcnt_hi(
                        (unsigned)(mask >> 32),
                        __builtin_amdgcn_mbcnt_lo((unsigned)mask, 0u));
                    if (keep) {
                        int slot = colB + prefix;
                        if (slot < KNN) ob[slot] = sub + lane;
                    }
                    colB += (int)__popcll(mask);
                }
            }
        }
        if (colA >= KNN && colB >= KNN) break;      // wave-uniform early exit
    }

    // Pad tail slots [collected, 32) with the first neighbor index.
    if (colA < KNN) {
        int slot = colA + lane;
        if (slot < KNN) oa[slot] = firstA;
    }
    if (colB < KNN) {
        int slot = colB + lane;
        if (slot < KNN) ob[slot] = firstB;
    }
}

extern "C" void kernel_launch(void* const* d_in, const int* in_sizes, int n_in,
                              void* d_out, int out_size, void* d_ws, size_t ws_size,
                              hipStream_t stream) {
    const float* pos       = (const float*)d_in[0];   // (8, 8192, 3) f32
    const int*   centroids = (const int*)d_in[1];     // (8, 2048) int32 on device
    int*         out       = (int*)d_out;             // (8, 2048, 32) int32

    float4* pack = (float4*)d_ws;                     // 8*8192*16B = 1 MiB scratch

    const int total = NBATCH * NPTS;                  // 65536 points
    gg_prep<<<dim3((total + 255) / 256), dim3(256), 0, stream>>>(pos, pack, total);

    const int nw = (NBATCH * NQ) / 2;                 // 8192 waves, 4 per block
    gg_ballquery<<<dim3(nw / 4), dim3(256), 0, stream>>>(pack, centroids, out);
}